// Round 4
// baseline (775.487 us; speedup 1.0000x reference)
//
#include <hip/hip_runtime.h>
#include <hip/hip_bf16.h>

// B=1024, L=160, D=300. Outputs (proj_T, HCD) fp32.
// Algebra (validated R1/R2, absmax 0.031):
//   projT = T @ Wproj^T + b                          (fp32 -> d_out)
//   pCD   = CD @ Wproj^T + b  (bf16 swz, col300=1)   (in-place over Abf CD-half)
//   ZT = sigmoid(projT . (Pmat^T mean_aug) + cT)     [gate_k]
//   Y = pCD @ MaugT^T  (bf16 swz -> Abf T-half)      [gemm_k mode 2]
//   S = Y @ pCD^T ; s_i = sum_j sigm(S_ij) ZT_j W3_j ; alpha=softmax(s)
//   HCD[i,:] = alpha_i * pCD[i,:]                    [finale_k; d_out write-only]
// R3 bug fixed: pCD no longer aliases the HCD output region (finale blocks
// clobbered other batches' pCD -> NaN). pCD now overwrites Abf's CD-half
// in-place: block m0 reads rows [m0,m0+256) before its epilogue writes the
// same rows; no cross-block row sharing -> race-free (G16).
// Global bf16 matrices carry a baked per-64-col-chunk swizzle: 16B group g of
// chunk stored at slot g^(row&7) -> global_load_lds stages linearly, ds_read
// applies the XOR -> conflict-free LDS reads (rule-21 both-sides pattern).

typedef __attribute__((ext_vector_type(8))) short short8;
typedef __attribute__((ext_vector_type(4))) float f32x4;

#define DP 320

__device__ __forceinline__ unsigned short f2bf(float x) {
  unsigned int u = __builtin_bit_cast(unsigned int, x);
  u += 0x7FFFu + ((u >> 16) & 1u);
  return (unsigned short)(u >> 16);
}
__device__ __forceinline__ float bf2f(unsigned short h) {
  unsigned int u = ((unsigned int)h) << 16;
  return __builtin_bit_cast(float, u);
}
__device__ __forceinline__ void gload16(const void* g, void* l) {
  __builtin_amdgcn_global_load_lds(
      (const __attribute__((address_space(1))) unsigned int*)g,
      (__attribute__((address_space(3))) unsigned int*)l, 16, 0, 0);
}
__device__ __forceinline__ float sigm(float x) { return 1.0f / (1.0f + __expf(-x)); }
// baked swizzle: column c of row r stored at column swzc(r,c)
__device__ __forceinline__ int swzc(int r, int c) {
  return (c & ~63) | ((((c >> 3) & 7) ^ (r & 7)) << 3) | (c & 7);
}

// ---- Wb[n][swzc] = bf16(Wproj[n][k]), zero-padded to 320x320 -----------------
__global__ void wb_k(const float* __restrict__ W, unsigned short* __restrict__ Wb) {
  int n = blockIdx.x, c = threadIdx.x;
  unsigned short v = (n < 300 && c < 300) ? f2bf(W[n * 300 + c]) : (unsigned short)0;
  Wb[n * DP + swzc(n, c)] = v;
}

// ---- out[n][c] = scale * sum_o A(c,o)*B(n,o); c==300 -> ba, n==300 -> bc -----
__global__ void crossdot_k(const float* __restrict__ Wa, const float* __restrict__ ba,
                           const float* __restrict__ Wc, const float* __restrict__ bc,
                           unsigned short* __restrict__ out_h, float* __restrict__ out_f,
                           float scale) {
  int n = blockIdx.x, c = threadIdx.x;
  float v = 0.f;
  if (n <= 300 && c <= 300) {
    for (int o = 0; o < 300; ++o) {
      float a = (c < 300) ? Wa[o * 300 + c] : ba[o];
      float b = (n < 300) ? Wc[o * 300 + n] : bc[o];
      v += a * b;
    }
    v *= scale;
  }
  if (out_h) out_h[n * DP + swzc(n, c)] = f2bf(v);  // bf16: swizzled (MFMA operand)
  else       out_f[n * DP + c] = v;                  // fp32: linear (gate_k)
}

// ---- cvt: T||CD fp32 -> Abf bf16 [327680][320], swizzle baked ----------------
__global__ __launch_bounds__(256)
void cvt_k(const float* __restrict__ T, const float* __restrict__ CD,
           unsigned short* __restrict__ Abf) {
  unsigned idx = blockIdx.x * 256 + threadIdx.x;   // 16B-group index
  if (idx >= 327680u * 40u) return;
  unsigned row = idx / 40u, G = idx - row * 40u;
  int kc = G >> 3, sg = G & 7;
  int col0 = kc * 64 + (sg ^ ((int)row & 7)) * 8;  // original cols this slot holds
  const float* base = (row < 163840u) ? T + (size_t)row * 300
                                      : CD + (size_t)(row - 163840u) * 300;
  short8 h;
  if (col0 + 8 <= 300) {
    f32x4 x0 = *(const f32x4*)(base + col0), x1 = *(const f32x4*)(base + col0 + 4);
#pragma unroll
    for (int j = 0; j < 4; ++j) { h[j] = (short)f2bf(x0[j]); h[j + 4] = (short)f2bf(x1[j]); }
  } else {
#pragma unroll
    for (int j = 0; j < 8; ++j) {
      int c = col0 + j;
      h[j] = (short)((c < 300) ? f2bf(base[c]) : (unsigned short)0);
    }
  }
  *(short8*)(Abf + (size_t)row * DP + G * 8) = h;
}

// ---- GEMM: 256x320 tile, BK=64, all-gload16, 2-phase counted pipeline --------
// mode 0: projT fp32 out (+bias); mode 1: pCD bf16 swz (+bias, col300=1)
// mode 2: Y = pCD @ MaugT^T, bf16 swz out
__global__ __launch_bounds__(512)
void gemm_k(const unsigned short* __restrict__ Abf, const unsigned short* __restrict__ pCDg,
            const unsigned short* __restrict__ Wb, const unsigned short* __restrict__ Maug,
            const float* __restrict__ bias, float* __restrict__ Of,
            unsigned short* __restrict__ pCDout, unsigned short* __restrict__ Yout,
            int mode_base) {
  __shared__ __align__(16) unsigned short As[2][256 * 64];
  __shared__ __align__(16) unsigned short Bs[2][320 * 64];
  const int tid = threadIdx.x, wid = tid >> 6, lane = tid & 63;
  const int lr = lane & 15, hi = lane >> 4;
  const int mode = mode_base + blockIdx.y;
  const unsigned short* __restrict__ A =
      (mode == 0) ? Abf : (mode == 1) ? Abf + (size_t)163840 * DP : pCDg;
  const unsigned short* __restrict__ Bm = (mode == 2) ? Maug : Wb;
  const size_t m0 = (size_t)blockIdx.x * 256;

  f32x4 acc[4][10];
#pragma unroll
  for (int i = 0; i < 4; ++i)
#pragma unroll
    for (int j = 0; j < 10; ++j) acc[i][j] = (f32x4){0.f, 0.f, 0.f, 0.f};

  auto stageA = [&](int buf, int kc) {
#pragma unroll
    for (int it = 0; it < 4; ++it) {
      int idx = it * 512 + tid;
      int row = idx >> 3, g = idx & 7;
      gload16(A + (m0 + row) * DP + kc * 64 + g * 8, (char*)As[buf] + idx * 16);
    }
  };
  auto stageB = [&](int buf, int kc) {
#pragma unroll
    for (int it = 0; it < 5; ++it) {
      int idx = it * 512 + tid;
      int row = idx >> 3, g = idx & 7;
      gload16(Bm + (size_t)row * DP + kc * 64 + g * 8, (char*)Bs[buf] + idx * 16);
    }
  };

  stageA(0, 0); stageB(0, 0);
  __syncthreads();
  int buf = 0;
  const int rm = (wid >> 1) * 64, cn = (wid & 1) * 160;
  for (int kc = 0; kc < 5; ++kc) {
    if (kc < 4) { stageA(buf ^ 1, kc + 1); stageB(buf ^ 1, kc + 1); }  // issue BEFORE compute
#pragma unroll
    for (int kk = 0; kk < 2; ++kk) {
      const int slot = ((kk * 4 + hi) ^ lr) & 7;     // row&7 == lr&7 for all frags
      short8 a[4];
#pragma unroll
      for (int mf = 0; mf < 4; ++mf)
        a[mf] = *(const short8*)((const char*)As[buf] + (rm + mf * 16 + lr) * 128 + slot * 16);
#pragma unroll
      for (int nh = 0; nh < 2; ++nh) {
        short8 b[5];
#pragma unroll
        for (int nf = 0; nf < 5; ++nf)
          b[nf] = *(const short8*)((const char*)Bs[buf] +
                                   (cn + (nh * 5 + nf) * 16 + lr) * 128 + slot * 16);
#pragma unroll
        for (int mf = 0; mf < 4; ++mf)
#pragma unroll
          for (int nf = 0; nf < 5; ++nf)
            acc[mf][nh * 5 + nf] =
                __builtin_amdgcn_mfma_f32_16x16x32_bf16(a[mf], b[nf], acc[mf][nh * 5 + nf], 0, 0, 0);
      }
    }
    __syncthreads();
    buf ^= 1;
  }

#pragma unroll
  for (int mf = 0; mf < 4; ++mf)
#pragma unroll
    for (int nf = 0; nf < 10; ++nf) {
      const int col = cn + nf * 16 + lr;
      const float bv = (mode < 2 && col < 300) ? bias[col] : 0.f;
#pragma unroll
      for (int r = 0; r < 4; ++r) {
        const size_t row = m0 + rm + mf * 16 + hi * 4 + r;
        float v = acc[mf][nf][r] + bv;
        if (mode == 0) {
          if (col < 300) Of[row * 300 + col] = v;
        } else {
          unsigned short u = (mode == 2) ? f2bf(v)
                           : (col < 300) ? f2bf(v)
                           : (col == 300) ? f2bf(1.0f) : (unsigned short)0;
          unsigned short* dst = (mode == 1) ? pCDout : Yout;
          dst[row * DP + swzc((int)row, col)] = u;
        }
      }
    }
}

// ---- gate: meanT + vT + ZT fused, one block per batch ------------------------
__global__ __launch_bounds__(320)
void gate_k(const float* __restrict__ projT, const float* __restrict__ Pmat,
            float* __restrict__ ZT) {
  __shared__ float mt[304];
  __shared__ float vv[304];
  const int b = blockIdx.x, tid = threadIdx.x, wid = tid >> 6, lane = tid & 63;
  const float* p = projT + (size_t)b * 48000;
  if (tid < 300) {
    float s = 0.f;
#pragma unroll 4
    for (int l = 0; l < 160; ++l) s += p[l * 300 + tid];
    mt[tid] = s * (1.0f / 160.0f);
  }
  __syncthreads();
  if (tid <= 300) {
    float s = Pmat[300 * DP + tid];
    for (int a = 0; a < 300; ++a) s += Pmat[a * DP + tid] * mt[a];
    vv[tid] = s;
  }
  __syncthreads();
  for (int j = wid * 32; j < wid * 32 + 32; ++j) {
    const float* row = p + j * 300;
    float s = 0.f;
    for (int c = lane; c < 300; c += 64) s += vv[c] * row[c];
#pragma unroll
    for (int m = 1; m < 64; m <<= 1) s += __shfl_xor(s, m, 64);
    if (lane == 0) ZT[b * 160 + j] = sigm(s + vv[300]);
  }
}

// ---- finale: S = Y @ pCD^T (pCD LDS-persistent), reduce, softmax, HCD --------
__global__ __launch_bounds__(320)
void finale_k(const unsigned short* __restrict__ Yg, const unsigned short* __restrict__ Pg,
              const float* __restrict__ ZT, const float* __restrict__ W3w,
              float* __restrict__ out) {
  __shared__ __align__(16) unsigned short Ps[160 * DP];     // 102400 B, swizzled
  __shared__ __align__(16) unsigned short Ys[2][160 * 64];  // 2x20480 B
  __shared__ float t_arr[160];
  __shared__ float s_arr[160];
  __shared__ float red0;
  const int b = blockIdx.x, tid = threadIdx.x, wid = tid >> 6, lane = tid & 63;
  const int lr = lane & 15, hi = lane >> 4;
  const unsigned short* Pb = Pg + (size_t)b * 160 * DP;
  const unsigned short* Yb = Yg + (size_t)b * 160 * DP;

  if (tid < 160) t_arr[tid] = ZT[b * 160 + tid] * W3w[tid];

#pragma unroll
  for (int it = 0; it < 20; ++it) {                 // Ps: pure linear copy
    int idx = it * 320 + tid;
    gload16(Pb + (size_t)idx * 8, (char*)Ps + idx * 16);
  }
  auto stageY = [&](int buf, int kc) {
#pragma unroll
    for (int it = 0; it < 4; ++it) {
      int idx = it * 320 + tid;
      int row = idx >> 3, g = idx & 7;
      gload16(Yb + (size_t)row * DP + kc * 64 + g * 8, (char*)Ys[buf] + idx * 16);
    }
  };

  f32x4 acc[2][10];
#pragma unroll
  for (int i = 0; i < 2; ++i)
#pragma unroll
    for (int j = 0; j < 10; ++j) acc[i][j] = (f32x4){0.f, 0.f, 0.f, 0.f};

  stageY(0, 0);
  __syncthreads();
  int buf = 0;
  const int rm = wid * 32;
  for (int kc = 0; kc < 5; ++kc) {
    if (kc < 4) stageY(buf ^ 1, kc + 1);
#pragma unroll
    for (int kk = 0; kk < 2; ++kk) {
      const int slot = ((kk * 4 + hi) ^ lr) & 7;
      short8 a[2], bb[10];
#pragma unroll
      for (int mf = 0; mf < 2; ++mf)
        a[mf] = *(const short8*)((const char*)Ys[buf] + (rm + mf * 16 + lr) * 128 + slot * 16);
#pragma unroll
      for (int nf = 0; nf < 10; ++nf)
        bb[nf] = *(const short8*)((const char*)Ps + (nf * 16 + lr) * 640 + (kc * 8 + slot) * 16);
#pragma unroll
      for (int mf = 0; mf < 2; ++mf)
#pragma unroll
        for (int nf = 0; nf < 10; ++nf)
          acc[mf][nf] = __builtin_amdgcn_mfma_f32_16x16x32_bf16(a[mf], bb[nf], acc[mf][nf], 0, 0, 0);
    }
    __syncthreads();
    buf ^= 1;
  }

  float pp[2][4];
#pragma unroll
  for (int mf = 0; mf < 2; ++mf)
#pragma unroll
    for (int r = 0; r < 4; ++r) {
      float s = 0.f;
#pragma unroll
      for (int nf = 0; nf < 10; ++nf) s += sigm(acc[mf][nf][r]) * t_arr[nf * 16 + lr];
      pp[mf][r] = s;
    }
#pragma unroll
  for (int m = 1; m < 16; m <<= 1)
#pragma unroll
    for (int mf = 0; mf < 2; ++mf)
#pragma unroll
      for (int r = 0; r < 4; ++r) pp[mf][r] += __shfl_xor(pp[mf][r], m, 64);
  if (lr == 0) {
#pragma unroll
    for (int mf = 0; mf < 2; ++mf)
#pragma unroll
      for (int r = 0; r < 4; ++r)
        s_arr[rm + mf * 16 + hi * 4 + r] = pp[mf][r];
  }
  __syncthreads();
  if (wid == 0) {
    float v0 = s_arr[lane], v1 = s_arr[lane + 64];
    float v2 = (lane < 32) ? s_arr[lane + 128] : -3.0e38f;
    float mx = fmaxf(fmaxf(v0, v1), v2);
#pragma unroll
    for (int m = 1; m < 64; m <<= 1) mx = fmaxf(mx, __shfl_xor(mx, m, 64));
    float e0 = __expf(v0 - mx), e1 = __expf(v1 - mx);
    float e2 = (lane < 32) ? __expf(v2 - mx) : 0.f;
    s_arr[lane] = e0; s_arr[lane + 64] = e1;
    if (lane < 32) s_arr[lane + 128] = e2;
    float sm = e0 + e1 + e2;
#pragma unroll
    for (int m = 1; m < 64; m <<= 1) sm += __shfl_xor(sm, m, 64);
    if (lane == 0) red0 = 1.0f / sm;
  }
  __syncthreads();
  const float inv = red0;
  float* ob = out + (size_t)b * 48000;
#pragma unroll 2
  for (int it = 0; it < 19; ++it) {
    int idx = it * 320 + tid;
    if (idx < 6080) {
      int i = idx / 38, cg = idx - i * 38;
      int sg = (cg & ~7) | ((cg & 7) ^ (i & 7));
      short8 pv = *(const short8*)((const char*)Ps + i * 640 + sg * 16);
      float sc = s_arr[i] * inv;
      int c0 = cg * 8;
#pragma unroll
      for (int j = 0; j < 8; ++j) {
        int c = c0 + j;
        if (c < 300) ob[(size_t)i * 300 + c] = sc * bf2f((unsigned short)pv[j]);
      }
    }
  }
}

extern "C" void kernel_launch(void* const* d_in, const int* in_sizes, int n_in,
                              void* d_out, int out_size, void* d_ws, size_t ws_size,
                              hipStream_t stream) {
  (void)in_sizes; (void)n_in; (void)out_size; (void)ws_size;
  const float* T      = (const float*)d_in[0];
  const float* CD     = (const float*)d_in[1];
  const float* Wproj  = (const float*)d_in[2];
  const float* bproj  = (const float*)d_in[3];
  const float* WqT_w  = (const float*)d_in[4];
  const float* WqT_b  = (const float*)d_in[5];
  const float* WqCD_w = (const float*)d_in[6];
  const float* WqCD_b = (const float*)d_in[7];
  const float* WkT_w  = (const float*)d_in[8];
  const float* WkT_b  = (const float*)d_in[9];
  const float* WkCD_w = (const float*)d_in[10];
  const float* WkCD_b = (const float*)d_in[11];
  const float* W3_w   = (const float*)d_in[12];
  // W3_b unused: softmax is shift-invariant.

  char* ws = (char*)d_ws;
  size_t off = 0;
  auto alloc = [&](size_t bytes) { void* p = ws + off; off = (off + bytes + 255) & ~(size_t)255; return p; };
  unsigned short* Abf   = (unsigned short*)alloc((size_t)327680 * DP * 2);  // 210 MB
  unsigned short* Wb    = (unsigned short*)alloc((size_t)DP * DP * 2);
  unsigned short* MaugT = (unsigned short*)alloc((size_t)DP * DP * 2);
  float* Pmat = (float*)alloc((size_t)DP * DP * 4);
  float* ZT   = (float*)alloc((size_t)1024 * 160 * 4);

  float* projT = (float*)d_out;
  float* HCD   = (float*)d_out + (size_t)49152000;       // write-only now
  unsigned short* pCDg = Abf + (size_t)163840 * DP;      // in-place over CD-half
  unsigned short* Yg   = Abf;                            // Y overwrites T-half (consumed)

  const float isd = 1.0f / sqrtf(300.0f);

  wb_k<<<dim3(320), dim3(320), 0, stream>>>(Wproj, Wb);
  crossdot_k<<<dim3(320), dim3(320), 0, stream>>>(WqCD_w, WqCD_b, WkCD_w, WkCD_b, MaugT, nullptr, isd);
  crossdot_k<<<dim3(320), dim3(320), 0, stream>>>(WkT_w, WkT_b, WqT_w, WqT_b, nullptr, Pmat, isd);
  cvt_k<<<dim3(51200), dim3(256), 0, stream>>>(T, CD, Abf);

  gemm_k<<<dim3(640, 2), dim3(512), 0, stream>>>(Abf, pCDg, Wb, MaugT, bproj,
                                                 projT, pCDg, Yg, 0);
  gate_k<<<dim3(1024), dim3(320), 0, stream>>>(projT, Pmat, ZT);
  gemm_k<<<dim3(640, 1), dim3(512), 0, stream>>>(Abf, pCDg, Wb, MaugT, bproj,
                                                 projT, pCDg, Yg, 2);
  finale_k<<<dim3(1024), dim3(320), 0, stream>>>(Yg, pCDg, ZT, W3_w, HCD);
}

// Round 5
// 731.085 us; speedup vs baseline: 1.0607x; 1.0607x over previous
//
#include <hip/hip_runtime.h>
#include <hip/hip_bf16.h>

// B=1024, L=160, D=300. Outputs (proj_T, HCD) fp32.
// Algebra (R1-R4 validated, absmax 0.031; R5 adds two exact reductions):
//   projT = T @ Wproj^T + b                 (fp32 -> d_out, WRITE-ONLY now)
//   pCD   = CD @ Wproj^T + b (bf16 swz, col300=1)
//   gate from RAW T (mean commutes with linear):
//     mraw = mean_l T ; meanT = W mraw + b ; vT = Pmat^T [meanT;1]
//     wT = W^T vT ; c' = b.vT + cT ; ZT[j] = sigm(T_j . wT + c')
//   Y = pCD @ Maug^T  ==  CD @ G^T + h   (G = Maug.W, h = Maug.b_aug precomp)
//   S = Y @ pCD^T ; s_i = sum_j sigm(S_ij) ZT_j W3_j ; alpha = softmax(s)
//   HCD[i,:] = alpha_i * pCD[i,:]
// ws-adaptive: big path (ws >= ~425 MB): pCD/Y separate buffers, single
// 3-mode gemm dispatch. Fallback: R4's race-free in-place scheme.

typedef __attribute__((ext_vector_type(8))) short short8;
typedef __attribute__((ext_vector_type(4))) float f32x4;

#define DP 320

__device__ __forceinline__ unsigned short f2bf(float x) {
  unsigned int u = __builtin_bit_cast(unsigned int, x);
  u += 0x7FFFu + ((u >> 16) & 1u);
  return (unsigned short)(u >> 16);
}
__device__ __forceinline__ float bf2f(unsigned short h) {
  unsigned int u = ((unsigned int)h) << 16;
  return __builtin_bit_cast(float, u);
}
__device__ __forceinline__ void gload16(const void* g, void* l) {
  __builtin_amdgcn_global_load_lds(
      (const __attribute__((address_space(1))) unsigned int*)g,
      (__attribute__((address_space(3))) unsigned int*)l, 16, 0, 0);
}
__device__ __forceinline__ float sigm(float x) { return 1.0f / (1.0f + __expf(-x)); }
// baked swizzle: source col c of row r stored at col swzc(r,c) (bijective per row)
__device__ __forceinline__ int swzc(int r, int c) {
  return (c & ~63) | ((((c >> 3) & 7) ^ (r & 7)) << 3) | (c & 7);
}

// ---- prep1: job0 Wb(bf16 swz)+Wt(fp32 transpose); job1 Maug; job2 Pmat ------
__global__ __launch_bounds__(320)
void prep1_k(const float* __restrict__ W,
             const float* __restrict__ WqCD_w, const float* __restrict__ WqCD_b,
             const float* __restrict__ WkCD_w, const float* __restrict__ WkCD_b,
             const float* __restrict__ WqT_w, const float* __restrict__ WqT_b,
             const float* __restrict__ WkT_w, const float* __restrict__ WkT_b,
             unsigned short* __restrict__ Wb, float* __restrict__ Wt,
             unsigned short* __restrict__ MaugT, float* __restrict__ Maug_f,
             float* __restrict__ Pmat, float isd) {
  const int x = blockIdx.x, c = threadIdx.x;
  if (x < 320) {
    const int n = x;
    unsigned short v = (n < 300 && c < 300) ? f2bf(W[n * 300 + c]) : (unsigned short)0;
    Wb[n * DP + swzc(n, c)] = v;
    if (n < 300 && c < 300) Wt[c * 304 + n] = W[n * 300 + c];
  } else if (x < 640) {
    const int n = x - 320;
    float v = 0.f;
    if (n <= 300 && c <= 300) {
      for (int o = 0; o < 300; ++o) {
        float a = (c < 300) ? WqCD_w[o * 300 + c] : WqCD_b[o];
        float b = (n < 300) ? WkCD_w[o * 300 + n] : WkCD_b[o];
        v += a * b;
      }
      v *= isd;
    }
    MaugT[n * DP + swzc(n, c)] = f2bf(v);
    Maug_f[n * DP + c] = v;
  } else {
    const int n = x - 640;
    float v = 0.f;
    if (n <= 300 && c <= 300) {
      for (int o = 0; o < 300; ++o) {
        float a = (c < 300) ? WkT_w[o * 300 + c] : WkT_b[o];
        float b = (n < 300) ? WqT_w[o * 300 + n] : WqT_b[o];
        v += a * b;
      }
      v *= isd;
    }
    Pmat[n * DP + c] = v;
  }
}

// ---- prep2: G[n,o] = sum_c Maug[n,c] W[c,o] (bf16 swz); h[n] = Maug.b_aug ---
__global__ __launch_bounds__(320)
void gh_k(const float* __restrict__ Maug_f, const float* __restrict__ W,
          const float* __restrict__ bproj, unsigned short* __restrict__ Gswz,
          float* __restrict__ h) {
  const int n = blockIdx.x, o = threadIdx.x;
  float v = 0.f;
  if (o < 300) {
    for (int c = 0; c < 300; ++c) v += Maug_f[n * DP + c] * W[c * 300 + o];
  } else if (o == 300) {
    float s = 0.f;
    for (int c = 0; c < 300; ++c) s += Maug_f[n * DP + c] * bproj[c];
    h[n] = s + Maug_f[n * DP + 300];
  }
  Gswz[n * DP + swzc(n, o)] = (o < 300) ? f2bf(v) : (unsigned short)0;
}

// ---- cvt: T||CD fp32 -> Abf bf16 [327680][320], swizzle baked ----------------
__global__ __launch_bounds__(256)
void cvt_k(const float* __restrict__ T, const float* __restrict__ CD,
           unsigned short* __restrict__ Abf) {
  unsigned idx = blockIdx.x * 256 + threadIdx.x;   // 16B-group index
  if (idx >= 327680u * 40u) return;
  unsigned row = idx / 40u, G = idx - row * 40u;
  int kc = G >> 3, sg = G & 7;
  int col0 = kc * 64 + ((sg ^ ((int)row & 7)) << 3);
  const float* base = (row < 163840u) ? T + (size_t)row * 300
                                      : CD + (size_t)(row - 163840u) * 300;
  short8 h;
  if (col0 + 8 <= 300) {
    f32x4 x0 = *(const f32x4*)(base + col0), x1 = *(const f32x4*)(base + col0 + 4);
#pragma unroll
    for (int j = 0; j < 4; ++j) { h[j] = (short)f2bf(x0[j]); h[j + 4] = (short)f2bf(x1[j]); }
  } else {
#pragma unroll
    for (int j = 0; j < 8; ++j) {
      int c = col0 + j;
      h[j] = (short)((c < 300) ? f2bf(base[c]) : (unsigned short)0);
    }
  }
  *(short8*)(Abf + (size_t)row * DP + G * 8) = h;
}

// ---- GEMM: 256x320 tile, BK=64, all-gload16, 2-phase pipeline ----------------
// mode 0: A0 @ Wb -> projT fp32 (+bproj); mode 1: A1 @ Wb -> pCD bf16 swz
// mode 2: A2 @ B2 -> Y bf16 swz (+ybias if non-null)
__global__ __launch_bounds__(512)
void gemm_k(const unsigned short* __restrict__ A0, const unsigned short* __restrict__ A1,
            const unsigned short* __restrict__ A2,
            const unsigned short* __restrict__ B01, const unsigned short* __restrict__ B2,
            const float* __restrict__ bias, const float* __restrict__ ybias,
            float* __restrict__ Of, unsigned short* __restrict__ pCDout,
            unsigned short* __restrict__ Yout, int mode_base) {
  __shared__ __align__(16) unsigned short As[2][256 * 64];
  __shared__ __align__(16) unsigned short Bs[2][320 * 64];
  const int tid = threadIdx.x, wid = tid >> 6, lane = tid & 63;
  const int lr = lane & 15, hi = lane >> 4;
  const int mode = mode_base + blockIdx.y;
  const unsigned short* __restrict__ A = (mode == 0) ? A0 : (mode == 1) ? A1 : A2;
  const unsigned short* __restrict__ Bm = (mode == 2) ? B2 : B01;
  const size_t m0 = (size_t)blockIdx.x * 256;

  f32x4 acc[4][10];
#pragma unroll
  for (int i = 0; i < 4; ++i)
#pragma unroll
    for (int j = 0; j < 10; ++j) acc[i][j] = (f32x4){0.f, 0.f, 0.f, 0.f};

  auto stageA = [&](int buf, int kc) {
#pragma unroll
    for (int it = 0; it < 4; ++it) {
      int idx = it * 512 + tid;
      int row = idx >> 3, g = idx & 7;
      gload16(A + (m0 + row) * DP + kc * 64 + g * 8, (char*)As[buf] + idx * 16);
    }
  };
  auto stageB = [&](int buf, int kc) {
#pragma unroll
    for (int it = 0; it < 5; ++it) {
      int idx = it * 512 + tid;
      int row = idx >> 3, g = idx & 7;
      gload16(Bm + (size_t)row * DP + kc * 64 + g * 8, (char*)Bs[buf] + idx * 16);
    }
  };

  stageA(0, 0); stageB(0, 0);
  __syncthreads();
  int buf = 0;
  const int rm = (wid >> 1) * 64, cn = (wid & 1) * 160;
  for (int kc = 0; kc < 5; ++kc) {
    if (kc < 4) { stageA(buf ^ 1, kc + 1); stageB(buf ^ 1, kc + 1); }
#pragma unroll
    for (int kk = 0; kk < 2; ++kk) {
      const int slot = ((kk * 4 + hi) ^ lr) & 7;
      short8 a[4];
#pragma unroll
      for (int mf = 0; mf < 4; ++mf)
        a[mf] = *(const short8*)((const char*)As[buf] + (rm + mf * 16 + lr) * 128 + slot * 16);
#pragma unroll
      for (int nh = 0; nh < 2; ++nh) {
        short8 b[5];
#pragma unroll
        for (int nf = 0; nf < 5; ++nf)
          b[nf] = *(const short8*)((const char*)Bs[buf] +
                                   (cn + (nh * 5 + nf) * 16 + lr) * 128 + slot * 16);
#pragma unroll
        for (int mf = 0; mf < 4; ++mf)
#pragma unroll
          for (int nf = 0; nf < 5; ++nf)
            acc[mf][nh * 5 + nf] =
                __builtin_amdgcn_mfma_f32_16x16x32_bf16(a[mf], b[nf], acc[mf][nh * 5 + nf], 0, 0, 0);
      }
    }
    __syncthreads();
    buf ^= 1;
  }

#pragma unroll
  for (int mf = 0; mf < 4; ++mf)
#pragma unroll
    for (int nf = 0; nf < 10; ++nf) {
      const int col = cn + nf * 16 + lr;
      float bv;
      if (mode == 2) bv = ybias ? ybias[col] : 0.f;
      else bv = (col < 300) ? bias[col] : 0.f;
#pragma unroll
      for (int r = 0; r < 4; ++r) {
        const size_t row = m0 + rm + mf * 16 + hi * 4 + r;
        float v = acc[mf][nf][r] + bv;
        if (mode == 0) {
          if (col < 300) Of[row * 300 + col] = v;
        } else {
          unsigned short u = (mode == 2) ? f2bf(v)
                           : (col < 300) ? f2bf(v)
                           : (col == 300) ? f2bf(1.0f) : (unsigned short)0;
          unsigned short* dst = (mode == 1) ? pCDout : Yout;
          dst[row * DP + swzc((int)row, col)] = u;
        }
      }
    }
}

// ---- gate2: mean(T) -> meanT -> vT -> wT -> ZT, all from bf16 T-half ---------
__global__ __launch_bounds__(320)
void gate2_k(const unsigned short* __restrict__ AbfT, const float* __restrict__ Pmat,
             const float* __restrict__ W, const float* __restrict__ Wt,
             const float* __restrict__ bproj, float* __restrict__ ZT) {
  __shared__ float part[8][320];
  __shared__ float ml[320];
  __shared__ float maug[304];
  __shared__ float vv[304];
  __shared__ float wt[320];
  __shared__ float cpr;
  const int b = blockIdx.x, t = threadIdx.x;
  const int wid = t >> 6, lane = t & 63;
  const size_t sbase = (size_t)b * 160 * DP;
  // A: per-column sums of the (swizzled) bf16 stripe
  {
    const int og = t % 40, seg = t / 40;
    float a8[8] = {0.f, 0.f, 0.f, 0.f, 0.f, 0.f, 0.f, 0.f};
    for (int l = seg * 20; l < seg * 20 + 20; ++l) {
      int sg = (og & ~7) | ((og & 7) ^ (l & 7));
      short8 v = *(const short8*)(AbfT + sbase + (size_t)l * DP + sg * 8);
#pragma unroll
      for (int j = 0; j < 8; ++j) a8[j] += bf2f((unsigned short)v[j]);
    }
#pragma unroll
    for (int j = 0; j < 8; ++j) part[seg][og * 8 + j] = a8[j];
  }
  __syncthreads();
  {
    float s = 0.f;
#pragma unroll
    for (int sg = 0; sg < 8; ++sg) s += part[sg][t];
    ml[t] = s * (1.0f / 160.0f);
  }
  __syncthreads();
  // B1: maug = W*ml + b (augmented with 1)
  if (t < 304) {
    if (t < 300) {
      float s = 0.f;
      for (int o = 0; o < 300; ++o) s += Wt[o * 304 + t] * ml[o];
      maug[t] = s + bproj[t];
    } else maug[t] = (t == 300) ? 1.f : 0.f;
  }
  __syncthreads();
  // B2: vv[c] = sum_{a<=300} Pmat[a][c] * maug[a]
  if (t < 304) {
    float s = 0.f;
    if (t <= 300) for (int a = 0; a <= 300; ++a) s += Pmat[a * DP + t] * maug[a];
    vv[t] = s;
  }
  __syncthreads();
  // B3: wt = W^T vv ; cpr = b.vv + vv[300]
  if (t < 320) {
    if (t < 300) {
      float s = 0.f;
      for (int c = 0; c < 300; ++c) s += vv[c] * W[c * 300 + t];
      wt[t] = s;
    } else {
      wt[t] = 0.f;
      if (t == 300) {
        float s = 0.f;
        for (int c = 0; c < 300; ++c) s += vv[c] * bproj[c];
        cpr = s + vv[300];
      }
    }
  }
  __syncthreads();
  // C: ZT[j] = sigm(T_j . wt + cpr)
  for (int j = wid * 32; j < wid * 32 + 32; ++j) {
    float s = 0.f;
    if (lane < 40) {
      int sg = (lane & ~7) | ((lane & 7) ^ (j & 7));
      short8 v = *(const short8*)(AbfT + sbase + (size_t)j * DP + sg * 8);
#pragma unroll
      for (int k = 0; k < 8; ++k) s += bf2f((unsigned short)v[k]) * wt[lane * 8 + k];
    }
#pragma unroll
    for (int m = 1; m < 64; m <<= 1) s += __shfl_xor(s, m, 64);
    if (lane == 0) ZT[b * 160 + j] = sigm(s + cpr);
  }
}

// ---- finale: S = Y @ pCD^T (pCD LDS-persistent), reduce, softmax, HCD --------
__global__ __launch_bounds__(320)
void finale_k(const unsigned short* __restrict__ Yg, const unsigned short* __restrict__ Pg,
              const float* __restrict__ ZT, const float* __restrict__ W3w,
              float* __restrict__ out) {
  __shared__ __align__(16) unsigned short Ps[160 * DP];
  __shared__ __align__(16) unsigned short Ys[2][160 * 64];
  __shared__ float t_arr[160];
  __shared__ float s_arr[160];
  __shared__ float red0;
  const int b = blockIdx.x, tid = threadIdx.x, wid = tid >> 6, lane = tid & 63;
  const int lr = lane & 15, hi = lane >> 4;
  const unsigned short* Pb = Pg + (size_t)b * 160 * DP;
  const unsigned short* Yb = Yg + (size_t)b * 160 * DP;

  if (tid < 160) t_arr[tid] = ZT[b * 160 + tid] * W3w[tid];

#pragma unroll
  for (int it = 0; it < 20; ++it) {
    int idx = it * 320 + tid;
    gload16(Pb + (size_t)idx * 8, (char*)Ps + idx * 16);
  }
  auto stageY = [&](int buf, int kc) {
#pragma unroll
    for (int it = 0; it < 4; ++it) {
      int idx = it * 320 + tid;
      int row = idx >> 3, g = idx & 7;
      gload16(Yb + (size_t)row * DP + kc * 64 + g * 8, (char*)Ys[buf] + idx * 16);
    }
  };

  f32x4 acc[2][10];
#pragma unroll
  for (int i = 0; i < 2; ++i)
#pragma unroll
    for (int j = 0; j < 10; ++j) acc[i][j] = (f32x4){0.f, 0.f, 0.f, 0.f};

  stageY(0, 0);
  __syncthreads();
  int buf = 0;
  const int rm = wid * 32;
  for (int kc = 0; kc < 5; ++kc) {
    if (kc < 4) stageY(buf ^ 1, kc + 1);
#pragma unroll
    for (int kk = 0; kk < 2; ++kk) {
      const int slot = ((kk * 4 + hi) ^ lr) & 7;
      short8 a[2], bb[10];
#pragma unroll
      for (int mf = 0; mf < 2; ++mf)
        a[mf] = *(const short8*)((const char*)Ys[buf] + (rm + mf * 16 + lr) * 128 + slot * 16);
#pragma unroll
      for (int nf = 0; nf < 10; ++nf)
        bb[nf] = *(const short8*)((const char*)Ps + (nf * 16 + lr) * 640 + (kc * 8 + slot) * 16);
#pragma unroll
      for (int mf = 0; mf < 2; ++mf)
#pragma unroll
        for (int nf = 0; nf < 10; ++nf)
          acc[mf][nf] = __builtin_amdgcn_mfma_f32_16x16x32_bf16(a[mf], bb[nf], acc[mf][nf], 0, 0, 0);
    }
    __syncthreads();
    buf ^= 1;
  }

  float pp[2][4];
#pragma unroll
  for (int mf = 0; mf < 2; ++mf)
#pragma unroll
    for (int r = 0; r < 4; ++r) {
      float s = 0.f;
#pragma unroll
      for (int nf = 0; nf < 10; ++nf) s += sigm(acc[mf][nf][r]) * t_arr[nf * 16 + lr];
      pp[mf][r] = s;
    }
#pragma unroll
  for (int m = 1; m < 16; m <<= 1)
#pragma unroll
    for (int mf = 0; mf < 2; ++mf)
#pragma unroll
      for (int r = 0; r < 4; ++r) pp[mf][r] += __shfl_xor(pp[mf][r], m, 64);
  if (lr == 0) {
#pragma unroll
    for (int mf = 0; mf < 2; ++mf)
#pragma unroll
      for (int r = 0; r < 4; ++r)
        s_arr[rm + mf * 16 + hi * 4 + r] = pp[mf][r];
  }
  __syncthreads();
  if (wid == 0) {
    float v0 = s_arr[lane], v1 = s_arr[lane + 64];
    float v2 = (lane < 32) ? s_arr[lane + 128] : -3.0e38f;
    float mx = fmaxf(fmaxf(v0, v1), v2);
#pragma unroll
    for (int m = 1; m < 64; m <<= 1) mx = fmaxf(mx, __shfl_xor(mx, m, 64));
    float e0 = __expf(v0 - mx), e1 = __expf(v1 - mx);
    float e2 = (lane < 32) ? __expf(v2 - mx) : 0.f;
    s_arr[lane] = e0; s_arr[lane + 64] = e1;
    if (lane < 32) s_arr[lane + 128] = e2;
    float sm = e0 + e1 + e2;
#pragma unroll
    for (int m = 1; m < 64; m <<= 1) sm += __shfl_xor(sm, m, 64);
    if (lane == 0) red0 = 1.0f / sm;
  }
  __syncthreads();
  const float inv = red0;
  float* ob = out + (size_t)b * 48000;
#pragma unroll 2
  for (int it = 0; it < 19; ++it) {
    int idx = it * 320 + tid;
    if (idx < 6080) {
      int i = idx / 38, cg = idx - i * 38;
      int sg = (cg & ~7) | ((cg & 7) ^ (i & 7));
      short8 pv = *(const short8*)((const char*)Ps + i * 640 + sg * 16);
      float sc = s_arr[i] * inv;
      int c0 = cg * 8;
#pragma unroll
      for (int j = 0; j < 8; ++j) {
        int c = c0 + j;
        if (c < 300) ob[(size_t)i * 300 + c] = sc * bf2f((unsigned short)pv[j]);
      }
    }
  }
}

extern "C" void kernel_launch(void* const* d_in, const int* in_sizes, int n_in,
                              void* d_out, int out_size, void* d_ws, size_t ws_size,
                              hipStream_t stream) {
  (void)in_sizes; (void)n_in; (void)out_size;
  const float* T      = (const float*)d_in[0];
  const float* CD     = (const float*)d_in[1];
  const float* Wproj  = (const float*)d_in[2];
  const float* bproj  = (const float*)d_in[3];
  const float* WqT_w  = (const float*)d_in[4];
  const float* WqT_b  = (const float*)d_in[5];
  const float* WqCD_w = (const float*)d_in[6];
  const float* WqCD_b = (const float*)d_in[7];
  const float* WkT_w  = (const float*)d_in[8];
  const float* WkT_b  = (const float*)d_in[9];
  const float* WkCD_w = (const float*)d_in[10];
  const float* WkCD_b = (const float*)d_in[11];
  const float* W3_w   = (const float*)d_in[12];
  // W3_b unused: softmax is shift-invariant.

  char* ws = (char*)d_ws;
  size_t off = 0;
  auto alloc = [&](size_t bytes) { void* p = ws + off; off = (off + bytes + 255) & ~(size_t)255; return p; };
  unsigned short* Wb     = (unsigned short*)alloc((size_t)DP * DP * 2);
  unsigned short* MaugT  = (unsigned short*)alloc((size_t)DP * DP * 2);
  unsigned short* Gswz   = (unsigned short*)alloc((size_t)DP * DP * 2);
  float* Maug_f = (float*)alloc((size_t)DP * DP * 4);
  float* Pmat   = (float*)alloc((size_t)DP * DP * 4);
  float* Wt     = (float*)alloc((size_t)304 * 304 * 4);
  float* hb     = (float*)alloc((size_t)DP * 4);
  float* ZT     = (float*)alloc((size_t)1024 * 160 * 4);
  unsigned short* Abf = (unsigned short*)alloc((size_t)327680 * DP * 2);  // ~210 MB
  unsigned short* AbfCD = Abf + (size_t)163840 * DP;

  const size_t half = (size_t)163840 * DP * 2;               // 104,857,600 B
  const bool big = (ws_size > off) && ((ws_size - off) >= 2 * half + 1024);
  unsigned short* pCDg = big ? (unsigned short*)alloc(half) : AbfCD;  // fallback: in-place CD-half
  unsigned short* Yg   = big ? (unsigned short*)alloc(half) : Abf;    // fallback: T-half (consumed)

  float* projT = (float*)d_out;
  float* HCD   = (float*)d_out + (size_t)49152000;

  const float isd = 1.0f / sqrtf(300.0f);

  prep1_k<<<dim3(960), dim3(320), 0, stream>>>(Wproj, WqCD_w, WqCD_b, WkCD_w, WkCD_b,
                                               WqT_w, WqT_b, WkT_w, WkT_b,
                                               Wb, Wt, MaugT, Maug_f, Pmat, isd);
  if (big)
    gh_k<<<dim3(320), dim3(320), 0, stream>>>(Maug_f, Wproj, bproj, Gswz, hb);
  cvt_k<<<dim3(51200), dim3(256), 0, stream>>>(T, CD, Abf);

  if (big) {
    // single 3-mode dispatch: projT, pCD, Y all independent (Y = CD@G^T + h)
    gemm_k<<<dim3(640, 3), dim3(512), 0, stream>>>(Abf, AbfCD, AbfCD, Wb, Gswz,
                                                   bproj, hb, projT, pCDg, Yg, 0);
    gate2_k<<<dim3(1024), dim3(320), 0, stream>>>(Abf, Pmat, Wproj, Wt, bproj, ZT);
    finale_k<<<dim3(1024), dim3(320), 0, stream>>>(Yg, pCDg, ZT, W3_w, HCD);
  } else {
    // R4-style: pCD in-place over CD-half; gate (reads T-half) BEFORE mode-2
    // overwrites T-half with Y. Race-free per-row in-place (G16-audited).
    gemm_k<<<dim3(640, 2), dim3(512), 0, stream>>>(Abf, AbfCD, nullptr, Wb, nullptr,
                                                   bproj, nullptr, projT, pCDg, nullptr, 0);
    gate2_k<<<dim3(1024), dim3(320), 0, stream>>>(Abf, Pmat, Wproj, Wt, bproj, ZT);
    gemm_k<<<dim3(640, 1), dim3(512), 0, stream>>>(Abf, AbfCD, pCDg, Wb, MaugT,
                                                   bproj, nullptr, projT, pCDg, Yg, 2);
    finale_k<<<dim3(1024), dim3(320), 0, stream>>>(Yg, pCDg, ZT, W3_w, HCD);
  }
}

// Round 6
// 688.819 us; speedup vs baseline: 1.1258x; 1.0614x over previous
//
#include <hip/hip_runtime.h>
#include <hip/hip_bf16.h>

// B=1024, L=160, D=300. Outputs (proj_T, HCD) fp32.
// Algebra (R1-R5 validated, absmax 0.031):
//   projT = T @ Wproj^T + b                 (fp32 -> d_out)
//   pCD   = CD @ Wproj^T + b (bf16 frag-order, col300=1)
//   gate from RAW fp32 T (mean commutes with linear):
//     mraw = mean_l T ; maug = W mraw + b ; vv = Pmat^T [maug;1]
//     wt = W^T vv ; c' = b.vv + vv[300] ; ZT[j] = sigm(T_j . wt + c')
//   Y = CD @ G^T + h   (G = Maug.W, h = Maug.b_aug; fallback: Y = pCD @ Maug^T)
//   S = Y @ pCD^T ; s_i = sum_j sigm(S_ij) ZT_j W3_j ; alpha = softmax(s)
//   HCD[i,:] = alpha_i * pCD[i,:]
//
// R6 layout: ALL bf16 matrices stored in MFMA-FRAGMENT ORDER.
//   A-side  [row16][kc][kk][lane=hi*16+lr][8]: lane holds A[row16*16+lr][kc*64+kk*32+hi*8+j]
//   B-side  [kc][col16][kk][lane][8] (kc-major so a K-slab is contiguous for staging)
// => GEMM A: global->VGPR direct (wave-private rows, coalesced 1KB frags, no LDS)
//    GEMM B: linear gload16 staging + lane-contiguous conflict-free ds_read_b128
//    LDS 80KB only -> 2 blocks/CU.

typedef __attribute__((ext_vector_type(8))) short short8;
typedef __attribute__((ext_vector_type(4))) float f32x4;

#define DP 320

__device__ __forceinline__ unsigned short f2bf(float x) {
  unsigned int u = __builtin_bit_cast(unsigned int, x);
  u += 0x7FFFu + ((u >> 16) & 1u);
  return (unsigned short)(u >> 16);
}
__device__ __forceinline__ float bf2f(unsigned short h) {
  unsigned int u = ((unsigned int)h) << 16;
  return __builtin_bit_cast(float, u);
}
__device__ __forceinline__ void gload16(const void* g, void* l) {
  __builtin_amdgcn_global_load_lds(
      (const __attribute__((address_space(1))) unsigned int*)g,
      (__attribute__((address_space(3))) unsigned int*)l, 16, 0, 0);
}
__device__ __forceinline__ float sigm(float x) { return 1.0f / (1.0f + __expf(-x)); }
// B-side fragment address (shorts) for element (col n, feat k)
__device__ __forceinline__ size_t baddr(int n, int k) {
  return (size_t)(k >> 6) * 20480 + (size_t)(n >> 4) * 1024 + ((k >> 5) & 1) * 512 +
         ((((k >> 3) & 3) << 4) | (n & 15)) * 8 + (k & 7);
}
// A-side fragment address (shorts) for element (row r, feat k), row16 = r>>4
__device__ __forceinline__ size_t aaddr(size_t r, int k) {
  return ((r >> 4) * 5 + (k >> 6)) * 1024 + ((k >> 5) & 1) * 512 +
         ((((k >> 3) & 3) << 4) | (r & 15)) * 8 + (k & 7);
}

// ---- prep1: job0 Wb(frag)+Wt; job1 Maug(frag+f32); job2 Pmat(f32) ------------
__global__ __launch_bounds__(320)
void prep1_k(const float* __restrict__ W,
             const float* __restrict__ WqCD_w, const float* __restrict__ WqCD_b,
             const float* __restrict__ WkCD_w, const float* __restrict__ WkCD_b,
             const float* __restrict__ WqT_w, const float* __restrict__ WqT_b,
             const float* __restrict__ WkT_w, const float* __restrict__ WkT_b,
             unsigned short* __restrict__ Wb, float* __restrict__ Wt,
             unsigned short* __restrict__ MaugT, float* __restrict__ Maug_f,
             float* __restrict__ Pmat, float isd) {
  const int x = blockIdx.x, c = threadIdx.x;
  if (x < 320) {
    const int n = x;
    unsigned short v = (n < 300 && c < 300) ? f2bf(W[n * 300 + c]) : (unsigned short)0;
    Wb[baddr(n, c)] = v;
    if (n < 300 && c < 300) Wt[c * 304 + n] = W[n * 300 + c];
  } else if (x < 640) {
    const int n = x - 320;
    float v = 0.f;
    if (n <= 300 && c <= 300) {
      for (int o = 0; o < 300; ++o) {
        float a = (c < 300) ? WqCD_w[o * 300 + c] : WqCD_b[o];
        float b = (n < 300) ? WkCD_w[o * 300 + n] : WkCD_b[o];
        v += a * b;
      }
      v *= isd;
    }
    MaugT[baddr(n, c)] = f2bf(v);
    Maug_f[n * DP + c] = v;
  } else {
    const int n = x - 640;
    float v = 0.f;
    if (n <= 300 && c <= 300) {
      for (int o = 0; o < 300; ++o) {
        float a = (c < 300) ? WkT_w[o * 300 + c] : WkT_b[o];
        float b = (n < 300) ? WqT_w[o * 300 + n] : WqT_b[o];
        v += a * b;
      }
      v *= isd;
    }
    Pmat[n * DP + c] = v;
  }
}

// ---- prep2: G[n,o] = sum_c Maug[n,c] W[c,o] (frag); h[n] = Maug.b_aug --------
__global__ __launch_bounds__(320)
void gh_k(const float* __restrict__ Maug_f, const float* __restrict__ W,
          const float* __restrict__ bproj, unsigned short* __restrict__ Gswz,
          float* __restrict__ h) {
  const int n = blockIdx.x, o = threadIdx.x;
  float v = 0.f;
  if (o < 300) {
    for (int c = 0; c < 300; ++c) v += Maug_f[n * DP + c] * W[c * 300 + o];
  } else if (o == 300) {
    float s = 0.f;
    for (int c = 0; c < 300; ++c) s += Maug_f[n * DP + c] * bproj[c];
    h[n] = s + Maug_f[n * DP + 300];
  }
  if (o > 300 && o == 301) { /* h for n handled above */ }
  Gswz[baddr(n, o)] = (o < 300) ? f2bf(v) : (unsigned short)0;
  if (o == 300 && n == 0) { /* nothing */ }
}

// ---- cvt: T||CD fp32 -> Abf bf16 fragment-order ------------------------------
__global__ __launch_bounds__(256)
void cvt_k(const float* __restrict__ T, const float* __restrict__ CD,
           unsigned short* __restrict__ Abf) {
  unsigned idx = blockIdx.x * 256 + threadIdx.x;   // 16B-chunk index
  if (idx >= 20480u * 640u) return;
  unsigned row16 = idx / 640u, rem = idx - row16 * 640u;
  int kc = rem >> 7, kk = (rem >> 6) & 1, lane = rem & 63;
  int lr = lane & 15, hi = lane >> 4;
  size_t row = (size_t)row16 * 16 + lr;
  int col0 = kc * 64 + kk * 32 + hi * 8;
  const float* base = (row < 163840u) ? T + row * 300 : CD + (row - 163840u) * 300;
  short8 h;
  if (col0 + 8 <= 300) {
    f32x4 x0 = *(const f32x4*)(base + col0), x1 = *(const f32x4*)(base + col0 + 4);
#pragma unroll
    for (int j = 0; j < 4; ++j) { h[j] = (short)f2bf(x0[j]); h[j + 4] = (short)f2bf(x1[j]); }
  } else {
#pragma unroll
    for (int j = 0; j < 8; ++j) {
      int c = col0 + j;
      h[j] = (short)((c < 300) ? f2bf(base[c]) : (unsigned short)0);
    }
  }
  *(short8*)(Abf + (size_t)idx * 8) = h;
}

// ---- GEMM: BM=128 (4 waves x 32 rows), BN=320, BK=64, A direct-to-reg --------
// mode 0: A0 @ Wb -> projT fp32 (+bproj); mode 1: A1 @ Wb -> pCD frag (+bproj, col300=1)
// mode 2: A2 @ B2 -> Y frag (+ybias if non-null)
__global__ __launch_bounds__(256, 2)
void gemm_k(const unsigned short* __restrict__ A0, const unsigned short* __restrict__ A1,
            const unsigned short* __restrict__ A2,
            const unsigned short* __restrict__ B01, const unsigned short* __restrict__ B2,
            const float* __restrict__ bias, const float* __restrict__ ybias,
            float* __restrict__ Of, unsigned short* __restrict__ pCDout,
            unsigned short* __restrict__ Yout, int mode_base) {
  __shared__ __align__(16) unsigned short Bs[2][20480];   // 2 x 40KB
  const int tid = threadIdx.x, wid = tid >> 6, lane = tid & 63;
  const int lr = lane & 15, hi = lane >> 4;
  const int mode = mode_base + blockIdx.y;
  const unsigned short* __restrict__ A = (mode == 0) ? A0 : (mode == 1) ? A1 : A2;
  const unsigned short* __restrict__ Bm = (mode == 2) ? B2 : B01;
  const size_t m0 = (size_t)blockIdx.x * 128;
  const size_t rt0 = (m0 >> 4) + wid * 2;   // wave's global row16 base (2 tiles)

  f32x4 acc[2][20];
#pragma unroll
  for (int i = 0; i < 2; ++i)
#pragma unroll
    for (int j = 0; j < 20; ++j) acc[i][j] = (f32x4){0.f, 0.f, 0.f, 0.f};

  auto stageB = [&](int buf, int kc) {
#pragma unroll
    for (int it = 0; it < 10; ++it) {
      int idx = it * 256 + tid;
      gload16(Bm + (size_t)kc * 20480 + (size_t)idx * 8, (char*)Bs[buf] + idx * 16);
    }
  };
  short8 af[2][2][2];   // [kc-buf][mf][kk]
  auto loadA = [&](short8 (&dst)[2][2], int kc) {
#pragma unroll
    for (int mf = 0; mf < 2; ++mf)
#pragma unroll
      for (int kk = 0; kk < 2; ++kk)
        dst[mf][kk] = *(const short8*)(A + ((rt0 + mf) * 5 + kc) * 1024 + kk * 512 + lane * 8);
  };

  stageB(0, 0);
  loadA(af[0], 0);
  __syncthreads();
#pragma unroll
  for (int kc = 0; kc < 5; ++kc) {
    const int cur = kc & 1;
    if (kc < 4) { stageB(cur ^ 1, kc + 1); loadA(af[cur ^ 1], kc + 1); }
#pragma unroll
    for (int kk = 0; kk < 2; ++kk)
#pragma unroll
      for (int nf = 0; nf < 20; ++nf) {
        short8 bb = *(const short8*)&Bs[cur][nf * 1024 + kk * 512 + lane * 8];
#pragma unroll
        for (int mf = 0; mf < 2; ++mf)
          acc[mf][nf] = __builtin_amdgcn_mfma_f32_16x16x32_bf16(af[cur][mf][kk], bb, acc[mf][nf], 0, 0, 0);
      }
    __syncthreads();
  }

#pragma unroll
  for (int mf = 0; mf < 2; ++mf)
#pragma unroll
    for (int nf = 0; nf < 20; ++nf) {
      const int col = nf * 16 + lr;
      const float bv = (mode == 2) ? (ybias ? ybias[col] : 0.f)
                                   : ((col < 300) ? bias[col] : 0.f);
      const size_t row16o = rt0 + mf;
#pragma unroll
      for (int r = 0; r < 4; ++r) {
        const size_t row = (row16o << 4) + hi * 4 + r;
        float v = acc[mf][nf][r] + bv;
        if (mode == 0) {
          if (col < 300) Of[row * 300 + col] = v;
        } else {
          unsigned short u = (mode == 2) ? f2bf(v)
                           : (col < 300) ? f2bf(v)
                           : (col == 300) ? f2bf(1.0f) : (unsigned short)0;
          unsigned short* dst = (mode == 1) ? pCDout : Yout;
          dst[(row16o * 5 + (col >> 6)) * 1024 + ((col >> 5) & 1) * 512 +
              ((((col >> 3) & 3) << 4) | (hi * 4 + r)) * 8 + (col & 7)] = u;
        }
      }
    }
}

// ---- gate2: mean(T) -> maug -> vv -> wt -> ZT, from RAW fp32 T ---------------
__global__ __launch_bounds__(320)
void gate2_k(const float* __restrict__ T, const float* __restrict__ Pmat,
             const float* __restrict__ W, const float* __restrict__ Wt,
             const float* __restrict__ bproj, float* __restrict__ ZT) {
  __shared__ float mt[304];
  __shared__ float maug[304];
  __shared__ float vv[304];
  __shared__ float wt[304];
  __shared__ float cpr;
  const int b = blockIdx.x, t = threadIdx.x;
  const int wid = t >> 6, lane = t & 63;
  const float* Tb = T + (size_t)b * 48000;
  if (t < 300) {
    float s = 0.f;
#pragma unroll 4
    for (int l = 0; l < 160; ++l) s += Tb[l * 300 + t];
    mt[t] = s * (1.0f / 160.0f);
  }
  __syncthreads();
  if (t < 304) {
    if (t < 300) {
      float s = 0.f;
      for (int o = 0; o < 300; ++o) s += Wt[o * 304 + t] * mt[o];
      maug[t] = s + bproj[t];
    } else maug[t] = (t == 300) ? 1.f : 0.f;
  }
  __syncthreads();
  if (t < 304) {
    float s = 0.f;
    if (t <= 300) for (int a = 0; a <= 300; ++a) s += Pmat[a * DP + t] * maug[a];
    vv[t] = s;
  }
  __syncthreads();
  if (t < 304) {
    if (t < 300) {
      float s = 0.f;
      for (int c = 0; c < 300; ++c) s += vv[c] * W[c * 300 + t];
      wt[t] = s;
    } else {
      wt[t] = 0.f;
      if (t == 300) {
        float s = 0.f;
        for (int c = 0; c < 300; ++c) s += vv[c] * bproj[c];
        cpr = s + vv[300];
      }
    }
  }
  __syncthreads();
  for (int j = wid * 32; j < wid * 32 + 32; ++j) {
    const float* row = Tb + j * 300;
    float s = 0.f;
    for (int c = lane; c < 300; c += 64) s += wt[c] * row[c];
#pragma unroll
    for (int m = 1; m < 64; m <<= 1) s += __shfl_xor(s, m, 64);
    if (lane == 0) ZT[b * 160 + j] = sigm(s + cpr);
  }
}

// ---- finale: S = Y @ pCD^T, reduce, softmax, HCD -----------------------------
// Ps LDS layout: [kc][row16][kk][lane][8] (kc*10240 + r16*1024 + ... shorts)
__global__ __launch_bounds__(640)
void finale_k(const unsigned short* __restrict__ Yg, const unsigned short* __restrict__ Pg,
              const float* __restrict__ ZT, const float* __restrict__ W3w,
              float* __restrict__ out) {
  __shared__ __align__(16) unsigned short Ps[51200];   // 100 KB
  __shared__ float t_arr[160];
  __shared__ float s_arr[160];
  __shared__ float red0;
  const int b = blockIdx.x, tid = threadIdx.x, wid = tid >> 6, lane = tid & 63;
  const int lr = lane & 15, hi = lane >> 4;
  const unsigned short* Pb = Pg + (size_t)b * 51200;
  const unsigned short* Yb = Yg + (size_t)b * 51200;

  if (tid < 160) t_arr[tid] = ZT[b * 160 + tid] * W3w[tid];

  auto stageP = [&](int kc) {
#pragma unroll
    for (int it = 0; it < 2; ++it) {
      int idx = it * 640 + tid;                  // 1280 chunks of 16B
      int r16 = idx >> 7, rem = idx & 127;
      gload16(Pb + ((size_t)r16 * 5 + kc) * 1024 + (size_t)rem * 8,
              (char*)Ps + ((size_t)kc * 10240 + (size_t)idx * 8) * 2);
    }
  };
  short8 yf[2][2];   // [kc-buf][kk]
  auto loadY = [&](short8 (&dst)[2], int kc) {
#pragma unroll
    for (int kk = 0; kk < 2; ++kk)
      dst[kk] = *(const short8*)(Yb + ((size_t)wid * 5 + kc) * 1024 + kk * 512 + lane * 8);
  };

  f32x4 acc[10];
#pragma unroll
  for (int j = 0; j < 10; ++j) acc[j] = (f32x4){0.f, 0.f, 0.f, 0.f};

  stageP(0);
  loadY(yf[0], 0);
  __syncthreads();
#pragma unroll
  for (int kc = 0; kc < 5; ++kc) {
    const int cur = kc & 1;
    if (kc < 4) { stageP(kc + 1); loadY(yf[cur ^ 1], kc + 1); }
#pragma unroll
    for (int kk = 0; kk < 2; ++kk)
#pragma unroll
      for (int nf = 0; nf < 10; ++nf) {
        short8 bb = *(const short8*)&Ps[kc * 10240 + nf * 1024 + kk * 512 + lane * 8];
        acc[nf] = __builtin_amdgcn_mfma_f32_16x16x32_bf16(yf[cur][kk], bb, acc[nf], 0, 0, 0);
      }
    __syncthreads();
  }

  float pp[4];
#pragma unroll
  for (int r = 0; r < 4; ++r) {
    float s = 0.f;
#pragma unroll
    for (int nf = 0; nf < 10; ++nf) s += sigm(acc[nf][r]) * t_arr[nf * 16 + lr];
    pp[r] = s;
  }
#pragma unroll
  for (int m = 1; m < 16; m <<= 1)
#pragma unroll
    for (int r = 0; r < 4; ++r) pp[r] += __shfl_xor(pp[r], m, 64);
  if (lr == 0) {
#pragma unroll
    for (int r = 0; r < 4; ++r) s_arr[wid * 16 + hi * 4 + r] = pp[r];
  }
  __syncthreads();
  if (wid == 0) {
    float v0 = s_arr[lane], v1 = s_arr[lane + 64];
    float v2 = (lane < 32) ? s_arr[lane + 128] : -3.0e38f;
    float mx = fmaxf(fmaxf(v0, v1), v2);
#pragma unroll
    for (int m = 1; m < 64; m <<= 1) mx = fmaxf(mx, __shfl_xor(mx, m, 64));
    float e0 = __expf(v0 - mx), e1 = __expf(v1 - mx);
    float e2 = (lane < 32) ? __expf(v2 - mx) : 0.f;
    s_arr[lane] = e0; s_arr[lane + 64] = e1;
    if (lane < 32) s_arr[lane + 128] = e2;
    float sm = e0 + e1 + e2;
#pragma unroll
    for (int m = 1; m < 64; m <<= 1) sm += __shfl_xor(sm, m, 64);
    if (lane == 0) red0 = 1.0f / sm;
  }
  __syncthreads();
  const float inv = red0;
  float* ob = out + (size_t)b * 48000;
#pragma unroll
  for (int it = 0; it < 10; ++it) {
    int idx = it * 640 + tid;                    // 6400 chunks: token i, 16B group g
    int i = idx / 40, g = idx - i * 40;
    int c0 = g * 8;
    if (c0 < 300) {
      short8 pv = *(const short8*)&Ps[(g >> 3) * 10240 + (i >> 4) * 1024 +
                                      ((g >> 2) & 1) * 512 + ((((g & 3) << 4) | (i & 15)) * 8)];
      float sc = s_arr[i] * inv;
      if (c0 + 8 <= 300) {
        f32x4 o0, o1;
#pragma unroll
        for (int j = 0; j < 4; ++j) { o0[j] = sc * bf2f((unsigned short)pv[j]); o1[j] = sc * bf2f((unsigned short)pv[j + 4]); }
        *(f32x4*)(ob + (size_t)i * 300 + c0) = o0;
        *(f32x4*)(ob + (size_t)i * 300 + c0 + 4) = o1;
      } else {
#pragma unroll
        for (int j = 0; j < 8; ++j) {
          int c = c0 + j;
          if (c < 300) ob[(size_t)i * 300 + c] = sc * bf2f((unsigned short)pv[j]);
        }
      }
    }
  }
}

extern "C" void kernel_launch(void* const* d_in, const int* in_sizes, int n_in,
                              void* d_out, int out_size, void* d_ws, size_t ws_size,
                              hipStream_t stream) {
  (void)in_sizes; (void)n_in; (void)out_size;
  const float* T      = (const float*)d_in[0];
  const float* CD     = (const float*)d_in[1];
  const float* Wproj  = (const float*)d_in[2];
  const float* bproj  = (const float*)d_in[3];
  const float* WqT_w  = (const float*)d_in[4];
  const float* WqT_b  = (const float*)d_in[5];
  const float* WqCD_w = (const float*)d_in[6];
  const float* WqCD_b = (const float*)d_in[7];
  const float* WkT_w  = (const float*)d_in[8];
  const float* WkT_b  = (const float*)d_in[9];
  const float* WkCD_w = (const float*)d_in[10];
  const float* WkCD_b = (const float*)d_in[11];
  const float* W3_w   = (const float*)d_in[12];
  // W3_b unused: softmax is shift-invariant.

  char* ws = (char*)d_ws;
  size_t off = 0;
  auto alloc = [&](size_t bytes) { void* p = ws + off; off = (off + bytes + 255) & ~(size_t)255; return p; };
  unsigned short* Wb     = (unsigned short*)alloc((size_t)DP * DP * 2);
  unsigned short* MaugT  = (unsigned short*)alloc((size_t)DP * DP * 2);
  unsigned short* Gswz   = (unsigned short*)alloc((size_t)DP * DP * 2);
  float* Maug_f = (float*)alloc((size_t)DP * DP * 4);
  float* Pmat   = (float*)alloc((size_t)DP * DP * 4);
  float* Wt     = (float*)alloc((size_t)304 * 304 * 4);
  float* hb     = (float*)alloc((size_t)DP * 4);
  float* ZT     = (float*)alloc((size_t)1024 * 160 * 4);
  unsigned short* Abf = (unsigned short*)alloc((size_t)327680 * DP * 2);  // ~210 MB
  unsigned short* AbfCD = Abf + (size_t)163840 * DP;

  const size_t half = (size_t)163840 * DP * 2;               // 104,857,600 B
  const bool big = (ws_size > off) && ((ws_size - off) >= 2 * half + 1024);
  unsigned short* pCDg = big ? (unsigned short*)alloc(half) : AbfCD;  // fallback: in-place CD-half
  unsigned short* Yg   = big ? (unsigned short*)alloc(half) : Abf;    // fallback: T-half (dead)

  float* projT = (float*)d_out;
  float* HCD   = (float*)d_out + (size_t)49152000;

  const float isd = 1.0f / sqrtf(300.0f);

  prep1_k<<<dim3(960), dim3(320), 0, stream>>>(Wproj, WqCD_w, WqCD_b, WkCD_w, WkCD_b,
                                               WqT_w, WqT_b, WkT_w, WkT_b,
                                               Wb, Wt, MaugT, Maug_f, Pmat, isd);
  gh_k<<<dim3(320), dim3(320), 0, stream>>>(Maug_f, Wproj, bproj, Gswz, hb);
  cvt_k<<<dim3(51200), dim3(256), 0, stream>>>(T, CD, Abf);
  gate2_k<<<dim3(1024), dim3(320), 0, stream>>>(T, Pmat, Wproj, Wt, bproj, ZT);

  if (big) {
    // single 3-mode dispatch: projT, pCD, Y all independent (Y = CD@G^T + h)
    gemm_k<<<dim3(1280, 3), dim3(256), 0, stream>>>(Abf, AbfCD, AbfCD, Wb, Gswz,
                                                    bproj, hb, projT, pCDg, Yg, 0);
  } else {
    // pCD written in-place over CD-half (per-row-slab, race-free); then
    // Y = pCD @ Maug^T (bias via pCD col300=1) over dead T-half.
    gemm_k<<<dim3(1280, 2), dim3(256), 0, stream>>>(Abf, AbfCD, nullptr, Wb, nullptr,
                                                    bproj, nullptr, projT, pCDg, nullptr, 0);
    gemm_k<<<dim3(1280, 1), dim3(256), 0, stream>>>(nullptr, nullptr, pCDg, Wb, MaugT,
                                                    bproj, nullptr, projT, nullptr, Yg, 2);
  }
  finale_k<<<dim3(1024), dim3(640), 0, stream>>>(Yg, pCDg, ZT, W3_w, HCD);
}

// Round 7
// 669.779 us; speedup vs baseline: 1.1578x; 1.0284x over previous
//
#include <hip/hip_runtime.h>
#include <hip/hip_bf16.h>

// B=1024, L=160, D=300. Outputs (proj_T, HCD) fp32.
// Algebra (validated R1-R6, absmax 0.031):
//   projT = T @ Wproj^T + b                  (fp32 -> d_out)      [gemm mode 0]
//   pCD   = CD @ Wproj^T + b  (bf16 frag-order, col300=1)         [gemm mode 1]
//   ZT    = sigm(T_j . wt + c')  via mean-commute algebra         [gate2_k]
//   Y     = pCD @ Maug^T  (bias via pCD col300=1)                 [gemm mode 2]
//   S = Y @ pCD^T ; s_i = sum_j sigm(S_ij) ZT_j W3_j ; alpha = softmax(s)
//   HCD[i,:] = alpha_i * pCD[i,:]                                 [finale_k]
//
// R7: cvt_k DELETED (modes 0/1 read fp32 + convert inline, T14 split:
// issue global->reg early, convert+ds_write after MFMA phase). gh_k DELETED
// (mode 2 reads pCD instead of CD-bf16). GEMM restructured m97-style:
// 8 waves (2x4), wave-tile 64x80 (acc 80 regs -> ~160 total, 8 waves/CU),
// A-reuse nf=5 / B-reuse mf=4 from LDS, dbuf 112 KB.
// All bf16 matrices in MFMA-fragment order (lane-contiguous ds_read_b128,
// linear gload16 staging; proven conflict-free in R6: SQ_LDS_BANK_CONFLICT=0).

typedef __attribute__((ext_vector_type(8))) short short8;
typedef __attribute__((ext_vector_type(4))) float f32x4;

#define DP 320

__device__ __forceinline__ unsigned short f2bf(float x) {
  unsigned int u = __builtin_bit_cast(unsigned int, x);
  u += 0x7FFFu + ((u >> 16) & 1u);
  return (unsigned short)(u >> 16);
}
__device__ __forceinline__ float bf2f(unsigned short h) {
  unsigned int u = ((unsigned int)h) << 16;
  return __builtin_bit_cast(float, u);
}
__device__ __forceinline__ void gload16(const void* g, void* l) {
  __builtin_amdgcn_global_load_lds(
      (const __attribute__((address_space(1))) unsigned int*)g,
      (__attribute__((address_space(3))) unsigned int*)l, 16, 0, 0);
}
__device__ __forceinline__ float sigm(float x) { return 1.0f / (1.0f + __expf(-x)); }
// B-side fragment address (shorts) for element (col n, feat k): kc-major
__device__ __forceinline__ size_t baddr(int n, int k) {
  return (size_t)(k >> 6) * 20480 + (size_t)(n >> 4) * 1024 + ((k >> 5) & 1) * 512 +
         ((((k >> 3) & 3) << 4) | (n & 15)) * 8 + (k & 7);
}
// A-side fragment address (shorts) for element (row r, feat k): row16-major
__device__ __forceinline__ size_t aaddr(size_t r, int k) {
  return ((r >> 4) * 5 + (k >> 6)) * 1024 + ((k >> 5) & 1) * 512 +
         ((((k >> 3) & 3) << 4) | (r & 15)) * 8 + (k & 7);
}

// ---- prep1: job0 Wb(frag)+Wt; job1 MaugT(frag); job2 Pmat(f32) ---------------
__global__ __launch_bounds__(320)
void prep1_k(const float* __restrict__ W,
             const float* __restrict__ WqCD_w, const float* __restrict__ WqCD_b,
             const float* __restrict__ WkCD_w, const float* __restrict__ WkCD_b,
             const float* __restrict__ WqT_w, const float* __restrict__ WqT_b,
             const float* __restrict__ WkT_w, const float* __restrict__ WkT_b,
             unsigned short* __restrict__ Wb, float* __restrict__ Wt,
             unsigned short* __restrict__ MaugT, float* __restrict__ Pmat,
             float isd) {
  const int x = blockIdx.x, c = threadIdx.x;
  if (x < 320) {
    const int n = x;
    unsigned short v = (n < 300 && c < 300) ? f2bf(W[n * 300 + c]) : (unsigned short)0;
    Wb[baddr(n, c)] = v;
    if (n < 300 && c < 300) Wt[c * 304 + n] = W[n * 300 + c];
  } else if (x < 640) {
    const int n = x - 320;
    float v = 0.f;
    if (n <= 300 && c <= 300) {
      for (int o = 0; o < 300; ++o) {
        float a = (c < 300) ? WqCD_w[o * 300 + c] : WqCD_b[o];
        float b = (n < 300) ? WkCD_w[o * 300 + n] : WkCD_b[o];
        v += a * b;
      }
      v *= isd;
    }
    MaugT[baddr(n, c)] = f2bf(v);
  } else {
    const int n = x - 640;
    float v = 0.f;
    if (n <= 300 && c <= 300) {
      for (int o = 0; o < 300; ++o) {
        float a = (c < 300) ? WkT_w[o * 300 + c] : WkT_b[o];
        float b = (n < 300) ? WqT_w[o * 300 + n] : WqT_b[o];
        v += a * b;
      }
      v *= isd;
    }
    Pmat[n * DP + c] = v;
  }
}

// ---- GEMM: 8 waves (2x4), BM=128, BN=320, BK=64, wave-tile 64x80 -------------
// mode 0: T  @ Wb  -> projT fp32 (+bproj)     [A: fp32, inline convert]
// mode 1: CD @ Wb  -> pCD bf16 frag (+bproj, col300=1)  [A: fp32, inline cvt]
// mode 2: pCD @ MaugT -> Y bf16 frag          [A: bf16 frag via gload16]
__global__ __launch_bounds__(512)
void gemm_k(const float* __restrict__ Tf, const float* __restrict__ CDf,
            const unsigned short* __restrict__ Ah,
            const unsigned short* __restrict__ B01,
            const unsigned short* __restrict__ B2,
            const float* __restrict__ bias,
            float* __restrict__ Of, unsigned short* __restrict__ pCDout,
            unsigned short* __restrict__ Yout, int mode_base) {
  __shared__ __align__(16) unsigned short As[2][8192];    // 2 x 16 KB
  __shared__ __align__(16) unsigned short Bs[2][20480];   // 2 x 40 KB
  const int tid = threadIdx.x, wid = tid >> 6, lane = tid & 63;
  const int lr = lane & 15, hi = lane >> 4;
  const int wr = wid >> 2, wc = wid & 3;
  const int mode = mode_base + blockIdx.y;
  const size_t m0 = (size_t)blockIdx.x * 128;
  const unsigned short* __restrict__ Bm = (mode == 2) ? B2 : B01;
  const float* __restrict__ Af = (mode == 0) ? Tf : CDf;

  f32x4 acc[4][5];
#pragma unroll
  for (int i = 0; i < 4; ++i)
#pragma unroll
    for (int j = 0; j < 5; ++j) acc[i][j] = (f32x4){0.f, 0.f, 0.f, 0.f};

  f32x4 ar[4];   // in-flight fp32 A (2 units x 8 floats)
  auto loadA = [&](int kc) {
#pragma unroll
    for (int u = 0; u < 2; ++u) {
      const int unit = tid * 2 + u;
      const int row = unit >> 3, cg = unit & 7;
      const int col0 = kc * 64 + cg * 8;
      const float* p = Af + (m0 + row) * 300 + col0;
      if (col0 + 8 <= 300) {
        ar[u * 2] = *(const f32x4*)p;
        ar[u * 2 + 1] = *(const f32x4*)(p + 4);
      } else {
#pragma unroll
        for (int j = 0; j < 4; ++j) {
          ar[u * 2][j] = (col0 + j < 300) ? p[j] : 0.f;
          ar[u * 2 + 1][j] = (col0 + 4 + j < 300) ? p[4 + j] : 0.f;
        }
      }
    }
  };
  auto writeA = [&](int buf) {
#pragma unroll
    for (int u = 0; u < 2; ++u) {
      const int unit = tid * 2 + u;
      const int row = unit >> 3, cg = unit & 7;
      short8 h;
#pragma unroll
      for (int j = 0; j < 4; ++j) {
        h[j] = (short)f2bf(ar[u * 2][j]);
        h[j + 4] = (short)f2bf(ar[u * 2 + 1][j]);
      }
      *(short8*)&As[buf][(size_t)(row >> 4) * 1024 + (size_t)(cg >> 2) * 512 +
                         ((((cg & 3) << 4) | (row & 15)) * 8)] = h;
    }
  };
  auto stageA2 = [&](int buf, int kc) {
#pragma unroll
    for (int it = 0; it < 2; ++it) {
      int idx = it * 512 + tid;
      gload16(Ah + (((m0 >> 4) + (idx >> 7)) * 5 + kc) * 1024 + (size_t)(idx & 127) * 8,
              (char*)As[buf] + (size_t)idx * 16);
    }
  };
  auto stageB = [&](int buf, int kc) {
#pragma unroll
    for (int it = 0; it < 5; ++it) {
      int idx = it * 512 + tid;
      gload16(Bm + (size_t)kc * 20480 + (size_t)idx * 8, (char*)Bs[buf] + (size_t)idx * 16);
    }
  };

  if (mode < 2) { loadA(0); stageB(0, 0); writeA(0); }
  else { stageA2(0, 0); stageB(0, 0); }
  __syncthreads();

  for (int kc = 0; kc < 5; ++kc) {
    const int cur = kc & 1;
    if (kc < 4) {
      if (mode < 2) loadA(kc + 1);       // issue A fp32 early (T14)
      else stageA2(cur ^ 1, kc + 1);
      stageB(cur ^ 1, kc + 1);
    }
#pragma unroll
    for (int kk = 0; kk < 2; ++kk) {
      short8 a[4], b[5];
#pragma unroll
      for (int mf = 0; mf < 4; ++mf)
        a[mf] = *(const short8*)&As[cur][(size_t)(wr * 4 + mf) * 1024 + kk * 512 + lane * 8];
#pragma unroll
      for (int nf = 0; nf < 5; ++nf)
        b[nf] = *(const short8*)&Bs[cur][(size_t)(wc * 5 + nf) * 1024 + kk * 512 + lane * 8];
#pragma unroll
      for (int mf = 0; mf < 4; ++mf)
#pragma unroll
        for (int nf = 0; nf < 5; ++nf)
          acc[mf][nf] = __builtin_amdgcn_mfma_f32_16x16x32_bf16(a[mf], b[nf], acc[mf][nf], 0, 0, 0);
    }
    if (kc < 4 && mode < 2) writeA(cur ^ 1);   // convert + ds_write late (T14)
    __syncthreads();
  }

#pragma unroll
  for (int mf = 0; mf < 4; ++mf) {
    const size_t rowb = m0 + wr * 64 + mf * 16 + hi * 4;
#pragma unroll
    for (int nf = 0; nf < 5; ++nf) {
      const int col = wc * 80 + nf * 16 + lr;
      const float bv = (mode < 2) ? ((col < 300) ? bias[col] : 0.f) : 0.f;
#pragma unroll
      for (int r = 0; r < 4; ++r) {
        const size_t rw = rowb + r;
        float v = acc[mf][nf][r] + bv;
        if (mode == 0) {
          if (col < 300) Of[rw * 300 + col] = v;
        } else if (mode == 1) {
          unsigned short u = (col < 300) ? f2bf(v)
                           : ((col == 300) ? f2bf(1.0f) : (unsigned short)0);
          pCDout[aaddr(rw, col)] = u;
        } else {
          Yout[aaddr(rw, col)] = f2bf(v);
        }
      }
    }
  }
}

// ---- gate2: mean(T) -> maug -> vv -> wt -> ZT, from RAW fp32 T ---------------
__global__ __launch_bounds__(320)
void gate2_k(const float* __restrict__ T, const float* __restrict__ Pmat,
             const float* __restrict__ W, const float* __restrict__ Wt,
             const float* __restrict__ bproj, float* __restrict__ ZT) {
  __shared__ float mt[304];
  __shared__ float maug[304];
  __shared__ float vv[304];
  __shared__ float wt[304];
  __shared__ float cpr;
  const int b = blockIdx.x, t = threadIdx.x;
  const int wid = t >> 6, lane = t & 63;
  const float* Tb = T + (size_t)b * 48000;
  if (t < 300) {
    float s = 0.f;
#pragma unroll 4
    for (int l = 0; l < 160; ++l) s += Tb[l * 300 + t];
    mt[t] = s * (1.0f / 160.0f);
  }
  __syncthreads();
  if (t < 304) {
    if (t < 300) {
      float s = 0.f;
      for (int o = 0; o < 300; ++o) s += Wt[o * 304 + t] * mt[o];
      maug[t] = s + bproj[t];
    } else maug[t] = (t == 300) ? 1.f : 0.f;
  }
  __syncthreads();
  if (t < 304) {
    float s = 0.f;
    if (t <= 300) for (int a = 0; a <= 300; ++a) s += Pmat[a * DP + t] * maug[a];
    vv[t] = s;
  }
  __syncthreads();
  if (t < 304) {
    if (t < 300) {
      float s = 0.f;
      for (int c = 0; c < 300; ++c) s += vv[c] * W[c * 300 + t];
      wt[t] = s;
    } else {
      wt[t] = 0.f;
      if (t == 300) {
        float s = 0.f;
        for (int c = 0; c < 300; ++c) s += vv[c] * bproj[c];
        cpr = s + vv[300];
      }
    }
  }
  __syncthreads();
  for (int j = wid * 32; j < wid * 32 + 32; ++j) {
    const float* row = Tb + j * 300;
    float s = 0.f;
    for (int c = lane; c < 300; c += 64) s += wt[c] * row[c];
#pragma unroll
    for (int m = 1; m < 64; m <<= 1) s += __shfl_xor(s, m, 64);
    if (lane == 0) ZT[b * 160 + j] = sigm(s + cpr);
  }
}

// ---- finale: S = Y @ pCD^T, reduce, softmax, HCD (unchanged from R6) ---------
__global__ __launch_bounds__(640)
void finale_k(const unsigned short* __restrict__ Yg, const unsigned short* __restrict__ Pg,
              const float* __restrict__ ZT, const float* __restrict__ W3w,
              float* __restrict__ out) {
  __shared__ __align__(16) unsigned short Ps[51200];   // 100 KB
  __shared__ float t_arr[160];
  __shared__ float s_arr[160];
  __shared__ float red0;
  const int b = blockIdx.x, tid = threadIdx.x, wid = tid >> 6, lane = tid & 63;
  const int lr = lane & 15, hi = lane >> 4;
  const unsigned short* Pb = Pg + (size_t)b * 51200;
  const unsigned short* Yb = Yg + (size_t)b * 51200;

  if (tid < 160) t_arr[tid] = ZT[b * 160 + tid] * W3w[tid];

  auto stageP = [&](int kc) {
#pragma unroll
    for (int it = 0; it < 2; ++it) {
      int idx = it * 640 + tid;
      int r16 = idx >> 7, rem = idx & 127;
      gload16(Pb + ((size_t)r16 * 5 + kc) * 1024 + (size_t)rem * 8,
              (char*)Ps + ((size_t)kc * 10240 + (size_t)idx * 8) * 2);
    }
  };
  short8 yf[2][2];
  auto loadY = [&](short8 (&dst)[2], int kc) {
#pragma unroll
    for (int kk = 0; kk < 2; ++kk)
      dst[kk] = *(const short8*)(Yb + ((size_t)wid * 5 + kc) * 1024 + kk * 512 + lane * 8);
  };

  f32x4 acc[10];
#pragma unroll
  for (int j = 0; j < 10; ++j) acc[j] = (f32x4){0.f, 0.f, 0.f, 0.f};

  stageP(0);
  loadY(yf[0], 0);
  __syncthreads();
#pragma unroll
  for (int kc = 0; kc < 5; ++kc) {
    const int cur = kc & 1;
    if (kc < 4) { stageP(kc + 1); loadY(yf[cur ^ 1], kc + 1); }
#pragma unroll
    for (int kk = 0; kk < 2; ++kk)
#pragma unroll
      for (int nf = 0; nf < 10; ++nf) {
        short8 bb = *(const short8*)&Ps[kc * 10240 + nf * 1024 + kk * 512 + lane * 8];
        acc[nf] = __builtin_amdgcn_mfma_f32_16x16x32_bf16(yf[cur][kk], bb, acc[nf], 0, 0, 0);
      }
    __syncthreads();
  }

  float pp[4];
#pragma unroll
  for (int r = 0; r < 4; ++r) {
    float s = 0.f;
#pragma unroll
    for (int nf = 0; nf < 10; ++nf) s += sigm(acc[nf][r]) * t_arr[nf * 16 + lr];
    pp[r] = s;
  }
#pragma unroll
  for (int m = 1; m < 16; m <<= 1)
#pragma unroll
    for (int r = 0; r < 4; ++r) pp[r] += __shfl_xor(pp[r], m, 64);
  if (lr == 0) {
#pragma unroll
    for (int r = 0; r < 4; ++r) s_arr[wid * 16 + hi * 4 + r] = pp[r];
  }
  __syncthreads();
  if (wid == 0) {
    float v0 = s_arr[lane], v1 = s_arr[lane + 64];
    float v2 = (lane < 32) ? s_arr[lane + 128] : -3.0e38f;
    float mx = fmaxf(fmaxf(v0, v1), v2);
#pragma unroll
    for (int m = 1; m < 64; m <<= 1) mx = fmaxf(mx, __shfl_xor(mx, m, 64));
    float e0 = __expf(v0 - mx), e1 = __expf(v1 - mx);
    float e2 = (lane < 32) ? __expf(v2 - mx) : 0.f;
    s_arr[lane] = e0; s_arr[lane + 64] = e1;
    if (lane < 32) s_arr[lane + 128] = e2;
    float sm = e0 + e1 + e2;
#pragma unroll
    for (int m = 1; m < 64; m <<= 1) sm += __shfl_xor(sm, m, 64);
    if (lane == 0) red0 = 1.0f / sm;
  }
  __syncthreads();
  const float inv = red0;
  float* ob = out + (size_t)b * 48000;
#pragma unroll
  for (int it = 0; it < 10; ++it) {
    int idx = it * 640 + tid;
    int i = idx / 40, g = idx - i * 40;
    int c0 = g * 8;
    if (c0 < 300) {
      short8 pv = *(const short8*)&Ps[(g >> 3) * 10240 + (i >> 4) * 1024 +
                                      ((g >> 2) & 1) * 512 + ((((g & 3) << 4) | (i & 15)) * 8)];
      float sc = s_arr[i] * inv;
      if (c0 + 8 <= 300) {
        f32x4 o0, o1;
#pragma unroll
        for (int j = 0; j < 4; ++j) { o0[j] = sc * bf2f((unsigned short)pv[j]); o1[j] = sc * bf2f((unsigned short)pv[j + 4]); }
        *(f32x4*)(ob + (size_t)i * 300 + c0) = o0;
        *(f32x4*)(ob + (size_t)i * 300 + c0 + 4) = o1;
      } else {
#pragma unroll
        for (int j = 0; j < 8; ++j) {
          int c = c0 + j;
          if (c < 300) ob[(size_t)i * 300 + c] = sc * bf2f((unsigned short)pv[j]);
        }
      }
    }
  }
}

extern "C" void kernel_launch(void* const* d_in, const int* in_sizes, int n_in,
                              void* d_out, int out_size, void* d_ws, size_t ws_size,
                              hipStream_t stream) {
  (void)in_sizes; (void)n_in; (void)out_size; (void)ws_size;
  const float* T      = (const float*)d_in[0];
  const float* CD     = (const float*)d_in[1];
  const float* Wproj  = (const float*)d_in[2];
  const float* bproj  = (const float*)d_in[3];
  const float* WqT_w  = (const float*)d_in[4];
  const float* WqT_b  = (const float*)d_in[5];
  const float* WqCD_w = (const float*)d_in[6];
  const float* WqCD_b = (const float*)d_in[7];
  const float* WkT_w  = (const float*)d_in[8];
  const float* WkT_b  = (const float*)d_in[9];
  const float* WkCD_w = (const float*)d_in[10];
  const float* WkCD_b = (const float*)d_in[11];
  const float* W3_w   = (const float*)d_in[12];
  // W3_b unused: softmax is shift-invariant.

  char* ws = (char*)d_ws;
  size_t off = 0;
  auto alloc = [&](size_t bytes) { void* p = ws + off; off = (off + bytes + 255) & ~(size_t)255; return p; };
  unsigned short* Wb    = (unsigned short*)alloc((size_t)DP * DP * 2);
  unsigned short* MaugT = (unsigned short*)alloc((size_t)DP * DP * 2);
  float* Pmat = (float*)alloc((size_t)DP * DP * 4);
  float* Wt   = (float*)alloc((size_t)304 * 304 * 4);
  float* ZT   = (float*)alloc((size_t)1024 * 160 * 4);
  unsigned short* pCDg = (unsigned short*)alloc((size_t)163840 * DP * 2);  // 100 MB
  unsigned short* Yg   = (unsigned short*)alloc((size_t)163840 * DP * 2);  // 100 MB
  // ws need ~211 MB; R5 confirmed ws >= ~430 MB (big path ran).

  float* projT = (float*)d_out;
  float* HCD   = (float*)d_out + (size_t)49152000;

  const float isd = 1.0f / sqrtf(300.0f);

  prep1_k<<<dim3(960), dim3(320), 0, stream>>>(Wproj, WqCD_w, WqCD_b, WkCD_w, WkCD_b,
                                               WqT_w, WqT_b, WkT_w, WkT_b,
                                               Wb, Wt, MaugT, Pmat, isd);
  // modes 0,1: projT + pCD from fp32 inputs (inline bf16 convert)
  gemm_k<<<dim3(1280, 2), dim3(512), 0, stream>>>(T, CD, nullptr, Wb, nullptr,
                                                  bproj, projT, pCDg, nullptr, 0);
  // mode 2: Y = pCD @ Maug^T
  gemm_k<<<dim3(1280, 1), dim3(512), 0, stream>>>(nullptr, nullptr, pCDg, nullptr, MaugT,
                                                  nullptr, nullptr, nullptr, Yg, 2);
  gate2_k<<<dim3(1024), dim3(320), 0, stream>>>(T, Pmat, Wproj, Wt, bproj, ZT);
  finale_k<<<dim3(1024), dim3(640), 0, stream>>>(Yg, pCDg, ZT, W3_w, HCD);
}